// Round 1
// baseline (1486.463 us; speedup 1.0000x reference)
//
#include <hip/hip_runtime.h>
#include <hip/hip_bf16.h>
#include <math.h>

// ---------------------------------------------------------------------------
// GFA encoder forward, fp32 reference-style implementation.
// B=16, C=256, H=W=56, Hp=Wp=28, N=784, heads=8, dh=32, E=4.
// ---------------------------------------------------------------------------

#define Bdim 16
#define Cdim 256
#define Hdim 56
#define Wdim 56
#define Np 784        // 28*28 tokens
#define NH 8
#define DH 32
#define M_TOK 12544   // B*Np
#define M_PIX 50176   // B*H*W

// ---------------------------------------------------------------------------
// K1: depthwise 3x3 conv + bias + residual, 2x2 avg pool, LayerNorm over C.
// One block (256 threads) per output token; writes t[B,N,C].
// ---------------------------------------------------------------------------
__global__ __launch_bounds__(256) void k_dwpool_ln(
    const float* __restrict__ x, const float* __restrict__ dww,
    const float* __restrict__ dwb, const float* __restrict__ g1,
    const float* __restrict__ b1, float* __restrict__ t) {
  const int n = blockIdx.x;   // 0..783
  const int b = blockIdx.y;   // 0..15
  const int c = threadIdx.x;  // 0..255
  const int a = n / 28, bb = n % 28;
  const int r0 = 2 * a - 1, c0 = 2 * bb - 1;
  const float* xp = x + (size_t)(b * Cdim + c) * (Hdim * Wdim);

  float w[9];
#pragma unroll
  for (int i = 0; i < 9; i++) w[i] = dww[c * 9 + i];

  float patch[4][4];
#pragma unroll
  for (int i = 0; i < 4; i++) {
    const int rr = r0 + i;
    const bool rok = (rr >= 0) && (rr < Hdim);
#pragma unroll
    for (int j = 0; j < 4; j++) {
      const int cc = c0 + j;
      patch[i][j] = (rok && cc >= 0 && cc < Wdim) ? xp[rr * Wdim + cc] : 0.0f;
    }
  }
  const float bias = dwb[c];
  float acc = 0.0f;
#pragma unroll
  for (int pi = 0; pi < 2; pi++)
#pragma unroll
    for (int pj = 0; pj < 2; pj++) {
      float conv = bias;
#pragma unroll
      for (int r = 0; r < 3; r++)
#pragma unroll
        for (int s = 0; s < 3; s++)
          conv = fmaf(patch[pi + r][pj + s], w[r * 3 + s], conv);
      acc += conv + patch[pi + 1][pj + 1];
    }
  const float v = acc * 0.25f;

  // LayerNorm over 256 channels (block reduce)
  __shared__ float red[4][2];
  __shared__ float mv[2];
  float s1 = v, s2 = v * v;
#pragma unroll
  for (int off = 32; off > 0; off >>= 1) {
    s1 += __shfl_down(s1, off);
    s2 += __shfl_down(s2, off);
  }
  const int wid = threadIdx.x >> 6, lane = threadIdx.x & 63;
  if (lane == 0) { red[wid][0] = s1; red[wid][1] = s2; }
  __syncthreads();
  if (threadIdx.x == 0) {
    const float a1 = red[0][0] + red[1][0] + red[2][0] + red[3][0];
    const float a2 = red[0][1] + red[1][1] + red[2][1] + red[3][1];
    const float m = a1 * (1.0f / 256.0f);
    const float var = a2 * (1.0f / 256.0f) - m * m;
    mv[0] = m;
    mv[1] = rsqrtf(var + 1e-6f);
  }
  __syncthreads();
  t[(size_t)(b * Np + n) * Cdim + c] = (v - mv[0]) * mv[1] * g1[c] + b1[c];
}

// ---------------------------------------------------------------------------
// Generic fp32 GEMM: C[m,n] = sum_k A'[m,k] * B'[k,n] + bias[n]  (+ epilogue)
// Tile 64x64, BK=16, 256 threads, 4x4 microtile.
// AMODE: 0 = plain A[M,K] row-major; 1 = LayerNorm(u) on the fly (stats,g,b)
// BMODE: 0 = B[N,K] row-major (NT);   1 = ct_w: elem(k,n)=B[k*1024+n*4+rs]
// EPI:   0 = bias store; 1 = bias + addp[m,n]; 2 = bias + exact GELU;
//        3 = conv-transpose quadrant scatter to NHWC (rs = blockIdx.z)
// ---------------------------------------------------------------------------
__device__ __forceinline__ float gelu_exact(float x) {
  return 0.5f * x * (1.0f + erff(x * 0.70710678118654752f));
}

template <int AMODE, int BMODE, int EPI>
__global__ __launch_bounds__(256) void gemm_k(
    const float* __restrict__ A, const float* __restrict__ B,
    const float* __restrict__ bias, float* __restrict__ C, int M, int N, int K,
    const float* __restrict__ stats, const float* __restrict__ lng,
    const float* __restrict__ lnb, const float* __restrict__ addp) {
  __shared__ float As[16][68];
  __shared__ float Bs[16][68];
  const int m0 = blockIdx.y * 64;
  const int n0 = blockIdx.x * 64;
  const int tid = threadIdx.x;
  const int tx = tid & 15, ty = tid >> 4;
  const int arow = tid >> 2, akq = tid & 3;

  float acc[4][4] = {};

  for (int k0 = 0; k0 < K; k0 += 16) {
    // ---- load A tile (transposed into As[k][m]) ----
    {
      float4 av;
      const float4 raw =
          *(const float4*)&A[(size_t)(m0 + arow) * K + k0 + akq * 4];
      if constexpr (AMODE == 1) {
        const float mean = stats[(m0 + arow) * 2];
        const float rstd = stats[(m0 + arow) * 2 + 1];
        const float4 g = *(const float4*)&lng[k0 + akq * 4];
        const float4 bb = *(const float4*)&lnb[k0 + akq * 4];
        av.x = (raw.x - mean) * rstd * g.x + bb.x;
        av.y = (raw.y - mean) * rstd * g.y + bb.y;
        av.z = (raw.z - mean) * rstd * g.z + bb.z;
        av.w = (raw.w - mean) * rstd * g.w + bb.w;
      } else {
        av = raw;
      }
      As[akq * 4 + 0][arow] = av.x;
      As[akq * 4 + 1][arow] = av.y;
      As[akq * 4 + 2][arow] = av.z;
      As[akq * 4 + 3][arow] = av.w;
    }
    // ---- load B tile ----
    if constexpr (BMODE == 0) {
      const float4 bv =
          *(const float4*)&B[(size_t)(n0 + arow) * K + k0 + akq * 4];
      Bs[akq * 4 + 0][arow] = bv.x;
      Bs[akq * 4 + 1][arow] = bv.y;
      Bs[akq * 4 + 2][arow] = bv.z;
      Bs[akq * 4 + 3][arow] = bv.w;
    } else {
      const int rs_ = blockIdx.z;
      const int j = tid & 63, kk = tid >> 6;
#pragma unroll
      for (int kv = 0; kv < 4; kv++)
        Bs[kk + kv * 4][j] =
            B[(size_t)(k0 + kk + kv * 4) * 1024 + (n0 + j) * 4 + rs_];
    }
    __syncthreads();
#pragma unroll
    for (int kk = 0; kk < 16; kk++) {
      const float4 a = *(const float4*)&As[kk][ty * 4];
      const float4 bv = *(const float4*)&Bs[kk][tx * 4];
      acc[0][0] = fmaf(a.x, bv.x, acc[0][0]);
      acc[0][1] = fmaf(a.x, bv.y, acc[0][1]);
      acc[0][2] = fmaf(a.x, bv.z, acc[0][2]);
      acc[0][3] = fmaf(a.x, bv.w, acc[0][3]);
      acc[1][0] = fmaf(a.y, bv.x, acc[1][0]);
      acc[1][1] = fmaf(a.y, bv.y, acc[1][1]);
      acc[1][2] = fmaf(a.y, bv.z, acc[1][2]);
      acc[1][3] = fmaf(a.y, bv.w, acc[1][3]);
      acc[2][0] = fmaf(a.z, bv.x, acc[2][0]);
      acc[2][1] = fmaf(a.z, bv.y, acc[2][1]);
      acc[2][2] = fmaf(a.z, bv.z, acc[2][2]);
      acc[2][3] = fmaf(a.z, bv.w, acc[2][3]);
      acc[3][0] = fmaf(a.w, bv.x, acc[3][0]);
      acc[3][1] = fmaf(a.w, bv.y, acc[3][1]);
      acc[3][2] = fmaf(a.w, bv.z, acc[3][2]);
      acc[3][3] = fmaf(a.w, bv.w, acc[3][3]);
    }
    __syncthreads();
  }

  // ---- epilogue ----
  const float4 bi = *(const float4*)&bias[n0 + tx * 4];
#pragma unroll
  for (int i = 0; i < 4; i++) {
    const int m = m0 + ty * 4 + i;
    float4 v;
    v.x = acc[i][0] + bi.x;
    v.y = acc[i][1] + bi.y;
    v.z = acc[i][2] + bi.z;
    v.w = acc[i][3] + bi.w;
    if constexpr (EPI == 1) {
      const float4 ad = *(const float4*)&addp[(size_t)m * N + n0 + tx * 4];
      v.x += ad.x; v.y += ad.y; v.z += ad.z; v.w += ad.w;
    }
    if constexpr (EPI == 2) {
      v.x = gelu_exact(v.x); v.y = gelu_exact(v.y);
      v.z = gelu_exact(v.z); v.w = gelu_exact(v.w);
    }
    if constexpr (EPI == 3) {
      const int rs_ = blockIdx.z;
      const int r = rs_ >> 1, s = rs_ & 1;
      const int bI = m / Np, nr = m % Np;
      const int aa = nr / 28, cc = nr % 28;
      const size_t o =
          ((size_t)(bI * Hdim + 2 * aa + r) * Wdim + (2 * cc + s)) * Cdim +
          n0 + tx * 4;
      *(float4*)&C[o] = v;
    } else {
      *(float4*)&C[(size_t)m * N + n0 + tx * 4] = v;
    }
  }
}

// ---------------------------------------------------------------------------
// Attention: one block per (b,h). q,k,v are [dh=32, N=784] slices of qkv.
// Pass 1: Gram S = q k^T (raw) + row norms; normalize, temp, mask, softmax.
// Pass 2: out = P v, streamed; write attout[B,N,C].
// ---------------------------------------------------------------------------
__global__ __launch_bounds__(256) void k_attn(
    const float* __restrict__ qkv, const float* __restrict__ mask_u,
    const float* __restrict__ temp, float* __restrict__ attout) {
  const int bh = blockIdx.x;
  const int b = bh >> 3, h = bh & 7;
  const int tid = threadIdx.x;
  __shared__ float qs[32][66], ks[32][66], vs[32][66];
  __shared__ float Smat[32][33];
  __shared__ float qn[32], kn[32];

  const size_t base = (size_t)b * Np * 768 + h * 32;
  const int d = tid >> 3, e4 = tid & 7;
  const int ld = tid & 31, lj = tid >> 5;

  float s4[4] = {0.f, 0.f, 0.f, 0.f};
  float nrm = 0.0f;

  for (int n0 = 0; n0 < Np; n0 += 64) {
#pragma unroll
    for (int it = 0; it < 8; it++) {
      const int j = lj + it * 8;
      const int n = n0 + j;
      float qv = 0.f, kv = 0.f;
      if (n < Np) {
        qv = qkv[base + (size_t)n * 768 + ld];
        kv = qkv[base + (size_t)n * 768 + 256 + ld];
      }
      qs[ld][j] = qv;
      ks[ld][j] = kv;
    }
    __syncthreads();
#pragma unroll 4
    for (int j = 0; j < 64; j++) {
      const float qv = qs[d][j];
#pragma unroll
      for (int u = 0; u < 4; u++) s4[u] = fmaf(qv, ks[e4 * 4 + u][j], s4[u]);
    }
    if (tid < 32) {
      for (int j = 0; j < 64; j++) { const float q = qs[tid][j]; nrm = fmaf(q, q, nrm); }
    } else if (tid < 64) {
      for (int j = 0; j < 64; j++) { const float kk = ks[tid - 32][j]; nrm = fmaf(kk, kk, nrm); }
    }
    __syncthreads();
  }

  if (tid < 32) qn[tid] = nrm;
  else if (tid < 64) kn[tid - 32] = nrm;
  __syncthreads();

  {
    const float tmp = temp[h];
    const float qd = fmaxf(sqrtf(qn[d]), 1e-12f);
#pragma unroll
    for (int u = 0; u < 4; u++) {
      const int e = e4 * 4 + u;
      const float ke = fmaxf(sqrtf(kn[e]), 1e-12f);
      float val = s4[u] / (qd * ke) * tmp;
      const float mu = mask_u[(size_t)bh * 1024 + d * 32 + e];
      if (mu < 0.2f) val -= 1e12f;
      Smat[d][e] = val;
    }
  }
  __syncthreads();

  if (tid < 32) {
    float mx = -1e30f;
#pragma unroll
    for (int e = 0; e < 32; e++) mx = fmaxf(mx, Smat[tid][e]);
    float ex[32];
    float sum = 0.f;
#pragma unroll
    for (int e = 0; e < 32; e++) {
      const float ev = expf(Smat[tid][e] - mx);
      ex[e] = ev;
      sum += ev;
    }
    const float inv = 1.0f / sum;
#pragma unroll
    for (int e = 0; e < 32; e++) Smat[tid][e] = ex[e] * inv;
  }
  __syncthreads();

  // pass 2
  const int d2 = tid & 31, jj = tid >> 5;
  float P[32];
#pragma unroll
  for (int e = 0; e < 32; e++) P[e] = Smat[d2][e];
  const size_t vbase = base + 512;
  const size_t obase = (size_t)b * Np * Cdim + h * 32;

  for (int n0 = 0; n0 < Np; n0 += 64) {
#pragma unroll
    for (int it = 0; it < 8; it++) {
      const int j = lj + it * 8;
      const int n = n0 + j;
      vs[ld][j] = (n < Np) ? qkv[vbase + (size_t)n * 768 + ld] : 0.f;
    }
    __syncthreads();
    float o[8] = {0.f, 0.f, 0.f, 0.f, 0.f, 0.f, 0.f, 0.f};
#pragma unroll
    for (int e = 0; e < 32; e++) {
      const float p = P[e];
#pragma unroll
      for (int u = 0; u < 8; u++) o[u] = fmaf(p, vs[e][jj * 8 + u], o[u]);
    }
#pragma unroll
    for (int u = 0; u < 8; u++) {
      const int n = n0 + jj * 8 + u;
      if (n < Np) attout[obase + (size_t)n * Cdim + d2] = o[u];
    }
    __syncthreads();
  }
}

// ---------------------------------------------------------------------------
// LN2 row statistics over u [M_PIX, 256] (NHWC rows): mean, rstd.
// One wave per row.
// ---------------------------------------------------------------------------
__global__ __launch_bounds__(256) void k_ln_stats(const float* __restrict__ u,
                                                  float* __restrict__ stats) {
  const int row = blockIdx.x * 4 + (threadIdx.x >> 6);
  const int lane = threadIdx.x & 63;
  const float4 v = *(const float4*)&u[(size_t)row * Cdim + lane * 4];
  float s1 = v.x + v.y + v.z + v.w;
  float s2 = v.x * v.x + v.y * v.y + v.z * v.z + v.w * v.w;
#pragma unroll
  for (int off = 32; off > 0; off >>= 1) {
    s1 += __shfl_down(s1, off);
    s2 += __shfl_down(s2, off);
  }
  if (lane == 0) {
    const float m = s1 * (1.0f / 256.0f);
    const float var = s2 * (1.0f / 256.0f) - m * m;
    stats[row * 2] = m;
    stats[row * 2 + 1] = rsqrtf(var + 1e-6f);
  }
}

// ---------------------------------------------------------------------------
// Final: out[b,c,h,w] = x[b,c,h,w] + y_nhwc[b,h,w,c]  (LDS transpose tile)
// ---------------------------------------------------------------------------
__global__ __launch_bounds__(256) void k_final(const float* __restrict__ x,
                                               const float* __restrict__ y,
                                               float* __restrict__ out) {
  __shared__ float tile[64][65];
  const int hw0 = blockIdx.x * 64;  // 49 tiles over 3136
  const int c0 = blockIdx.y * 64;   // 4
  const int b = blockIdx.z;
  const int tid = threadIdx.x;
  {
    const int ci = tid & 63;
    const int hwB = tid >> 6;
#pragma unroll
    for (int it = 0; it < 16; it++) {
      const int hwi = hwB + it * 4;
      tile[hwi][ci] = y[((size_t)b * 3136 + hw0 + hwi) * Cdim + c0 + ci];
    }
  }
  __syncthreads();
  {
    const int hwi = tid & 63;
    const int cB = tid >> 6;
#pragma unroll
    for (int it = 0; it < 16; it++) {
      const int ci = cB + it * 4;
      const size_t o = ((size_t)(b * Cdim + c0 + ci)) * 3136 + hw0 + hwi;
      out[o] = x[o] + tile[hwi][ci];
    }
  }
}

// ---------------------------------------------------------------------------
// Host launcher
// ---------------------------------------------------------------------------
extern "C" void kernel_launch(void* const* d_in, const int* in_sizes, int n_in,
                              void* d_out, int out_size, void* d_ws,
                              size_t ws_size, hipStream_t stream) {
  const float* x      = (const float*)d_in[0];
  const float* mask_u = (const float*)d_in[1];
  const float* dw_w   = (const float*)d_in[2];
  const float* dw_b   = (const float*)d_in[3];
  const float* g1     = (const float*)d_in[4];
  const float* b1     = (const float*)d_in[5];
  const float* qkv_w  = (const float*)d_in[6];
  const float* qkv_b  = (const float*)d_in[7];
  const float* temp   = (const float*)d_in[8];
  const float* proj_w = (const float*)d_in[9];
  const float* proj_b = (const float*)d_in[10];
  const float* ct_w   = (const float*)d_in[11];
  const float* ct_b   = (const float*)d_in[12];
  const float* g2     = (const float*)d_in[13];
  const float* b2     = (const float*)d_in[14];
  const float* pw1_w  = (const float*)d_in[15];
  const float* pw1_b  = (const float*)d_in[16];
  const float* pw2_w  = (const float*)d_in[17];
  const float* pw2_b  = (const float*)d_in[18];

  float* ws = (float*)d_ws;
  // workspace layout (float offsets); h1 reuses [0, 12845056) after t/qkv die
  float* t      = ws;                  // 3,211,264 floats
  float* qkvb   = ws + 3211264;        // 9,633,792
  float* attout = ws + 12845056;       // 3,211,264
  float* rbuf   = ws + 16056320;       // 3,211,264
  float* u      = ws + 19267584;       // 12,845,056 (NHWC; later holds y)
  float* stats  = ws + 32112640;       // 100,352
  float* h1     = ws;                  // 12,845,056 (chunk)
  float* out    = (float*)d_out;

  // 1) dwconv + residual + pool + LN1 -> t [B,N,C]
  k_dwpool_ln<<<dim3(Np, Bdim), 256, 0, stream>>>(x, dw_w, dw_b, g1, b1, t);

  // 2) qkv = t @ qkv_w^T + qkv_b   [12544, 768]
  gemm_k<0, 0, 0><<<dim3(12, 196), 256, 0, stream>>>(
      t, qkv_w, qkv_b, qkvb, M_TOK, 768, 256, nullptr, nullptr, nullptr,
      nullptr);

  // 3) attention -> attout [B,N,C]
  k_attn<<<dim3(128), 256, 0, stream>>>(qkvb, mask_u, temp, attout);

  // 4) r = t + attout @ proj_w^T + proj_b
  gemm_k<0, 0, 1><<<dim3(4, 196), 256, 0, stream>>>(
      attout, proj_w, proj_b, rbuf, M_TOK, 256, 256, nullptr, nullptr, nullptr,
      t);

  // 5) conv-transpose 2x2 stride-2 -> u NHWC [B,56,56,C]
  gemm_k<0, 1, 3><<<dim3(4, 196, 4), 256, 0, stream>>>(
      rbuf, ct_w, ct_b, u, M_TOK, 256, 256, nullptr, nullptr, nullptr, nullptr);

  // 6) LN2 stats per NHWC row
  k_ln_stats<<<dim3(M_PIX / 4), 256, 0, stream>>>(u, stats);

  // 7) MLP in 4 row-chunks; mlp2 writes y in-place over consumed u rows
  for (int ch = 0; ch < 4; ch++) {
    const float* uc = u + (size_t)ch * M_TOK * Cdim;
    const float* statsc = stats + (size_t)ch * M_TOK * 2;
    float* yc = (float*)uc;
    gemm_k<1, 0, 2><<<dim3(16, 196), 256, 0, stream>>>(
        uc, pw1_w, pw1_b, h1, M_TOK, 1024, 256, statsc, g2, b2, nullptr);
    gemm_k<0, 0, 0><<<dim3(4, 196), 256, 0, stream>>>(
        h1, pw2_w, pw2_b, yc, M_TOK, 256, 1024, nullptr, nullptr, nullptr,
        nullptr);
  }

  // 8) out = inp0 + y (NHWC -> NCHW)
  k_final<<<dim3(49, 4, Bdim), 256, 0, stream>>>(x, u, out);
}

// Round 3
// 574.042 us; speedup vs baseline: 2.5895x; 2.5895x over previous
//
#include <hip/hip_runtime.h>
#include <hip/hip_bf16.h>
#include <math.h>

// ---------------------------------------------------------------------------
// GFA encoder forward. bf16-MFMA GEMM pipeline.
// B=16, C=256, H=W=56, Hp=Wp=28, N=784, heads=8, dh=32, E=4.
// ---------------------------------------------------------------------------

#define Bdim 16
#define Cdim 256
#define Hdim 56
#define Wdim 56
#define Np 784
#define M_TOK 12544
#define M_PIX 50176

typedef __attribute__((ext_vector_type(8))) short short8;
typedef __attribute__((ext_vector_type(4))) float floatx4;

__device__ __forceinline__ float gelu_exact(float x) {
  return 0.5f * x * (1.0f + erff(x * 0.70710678118654752f));
}

// ---------------------------------------------------------------------------
// Weight prep: cast all GEMM weights to bf16 (ct_w restructured to [rs][n][k]).
// wb element offsets: qkv 0, proj 196608, pw1 262144, pw2 524288, ct 786432.
// ---------------------------------------------------------------------------
__global__ __launch_bounds__(256) void k_prep(
    const float* __restrict__ qkv_w, const float* __restrict__ proj_w,
    const float* __restrict__ pw1_w, const float* __restrict__ pw2_w,
    const float* __restrict__ ct_w, __hip_bfloat16* __restrict__ wb) {
  int i = blockIdx.x * 256 + threadIdx.x;
  if (i < 196608) { wb[i] = __float2bfloat16(qkv_w[i]); return; }
  i -= 196608;
  if (i < 65536) { (wb + 196608)[i] = __float2bfloat16(proj_w[i]); return; }
  i -= 65536;
  if (i < 262144) { (wb + 262144)[i] = __float2bfloat16(pw1_w[i]); return; }
  i -= 262144;
  if (i < 262144) { (wb + 524288)[i] = __float2bfloat16(pw2_w[i]); return; }
  i -= 262144;
  const int rs = i >> 16, rem = i & 65535, n = rem >> 8, k = rem & 255;
  (wb + 786432)[i] = __float2bfloat16(ct_w[k * 1024 + n * 4 + rs]);
}

// ---------------------------------------------------------------------------
// K1a: depthwise 3x3 + bias + residual + 2x2 avg pool. One block per (b,c)
// plane, LDS-staged with halo, fully coalesced. p is [B,C,28,28] fp32.
// ---------------------------------------------------------------------------
__global__ __launch_bounds__(256) void k_pool(const float* __restrict__ x,
                                              const float* __restrict__ dww,
                                              const float* __restrict__ dwb,
                                              float* __restrict__ p) {
  __shared__ float xs[58 * 60];
  const int bid = blockIdx.x;  // b*256 + c
  const int c = bid & 255;
  const int tid = threadIdx.x;
  const float* xp = x + (size_t)bid * 3136;
  for (int i = tid; i < 58 * 60; i += 256) xs[i] = 0.f;
  __syncthreads();
  for (int i = tid; i < 3136; i += 256) {
    const int r = i / 56, cc = i % 56;
    xs[(r + 1) * 60 + (cc + 1)] = xp[i];
  }
  __syncthreads();
  float w[9];
#pragma unroll
  for (int i = 0; i < 9; i++) w[i] = dww[c * 9 + i];
  const float bias = dwb[c];
  float* pp = p + (size_t)bid * Np;
  for (int n = tid; n < Np; n += 256) {
    const int a = n / 28, bb = n % 28;
    const int r0 = 2 * a, c0 = 2 * bb;
    float acc = 0.f;
#pragma unroll
    for (int pi = 0; pi < 2; pi++)
#pragma unroll
      for (int pj = 0; pj < 2; pj++) {
        float conv = bias;
#pragma unroll
        for (int rr = 0; rr < 3; rr++)
#pragma unroll
          for (int ss = 0; ss < 3; ss++)
            conv = fmaf(xs[(r0 + pi + rr) * 60 + c0 + pj + ss], w[rr * 3 + ss],
                        conv);
        acc += conv + xs[(r0 + pi + 1) * 60 + (c0 + pj + 1)];
      }
    pp[n] = acc * 0.25f;
  }
}

// ---------------------------------------------------------------------------
// K1b: transpose p [B,C,N] -> t [B,N,C] with LayerNorm over C. bf16 out.
// ---------------------------------------------------------------------------
__global__ __launch_bounds__(256) void k_lnt(const float* __restrict__ p,
                                             const float* __restrict__ g1,
                                             const float* __restrict__ b1,
                                             __hip_bfloat16* __restrict__ t) {
  __shared__ float xs[256][65];
  __shared__ float red[4][64][2];
  __shared__ float ms[64][2];
  const int n0 = blockIdx.x * 64;
  const int b = blockIdx.y;
  const int tid = threadIdx.x;
  const int lane = tid & 63, grp = tid >> 6;
  const int n = n0 + lane;
  const bool nok = (n < Np);
  float s1 = 0.f, s2 = 0.f;
  for (int it = 0; it < 64; it++) {
    const int c = grp * 64 + it;
    const float v = nok ? p[((size_t)b * Cdim + c) * Np + n] : 0.f;
    xs[c][lane] = v;
    s1 += v;
    s2 += v * v;
  }
  red[grp][lane][0] = s1;
  red[grp][lane][1] = s2;
  __syncthreads();
  if (tid < 64) {
    const float a1 =
        red[0][tid][0] + red[1][tid][0] + red[2][tid][0] + red[3][tid][0];
    const float a2 =
        red[0][tid][1] + red[1][tid][1] + red[2][tid][1] + red[3][tid][1];
    const float m = a1 * (1.f / 256.f);
    const float var = a2 * (1.f / 256.f) - m * m;
    ms[tid][0] = m;
    ms[tid][1] = rsqrtf(var + 1e-6f);
  }
  __syncthreads();
  const float gg = g1[tid], bb = b1[tid];
  const int nlim = (Np - n0 < 64) ? (Np - n0) : 64;
  for (int tok = 0; tok < nlim; tok++) {
    const float v = (xs[tid][tok] - ms[tok][0]) * ms[tok][1] * gg + bb;
    t[((size_t)b * Np + n0 + tok) * Cdim + tid] = __float2bfloat16(v);
  }
}

// ---------------------------------------------------------------------------
// bf16 MFMA GEMM: C[m,n] = A[M,K] @ W[N,K]^T + bias. 128x128 tile, BK=32,
// 4 waves 2x2, 16x16x32 MFMA, XOR-swizzled LDS, reg-prefetch pipeline.
// EPI: 0 bf16 store; 1 +resid bf16; 2 GELU bf16; 3 ct-quadrant scatter bf16.
// Requires M%128==0, N%128==0, K%32==0.
// NOTE (round-2 bug): staging chunks are 8 bf16 = 16 B -> must be int4,
// NOT ushort4 (8 B) — half-written LDS fed NaN bit patterns to MFMA.
// ---------------------------------------------------------------------------
template <int EPI>
__global__ __launch_bounds__(256) void mm_bf16(
    const __hip_bfloat16* __restrict__ A, const __hip_bfloat16* __restrict__ W,
    const float* __restrict__ bias, __hip_bfloat16* __restrict__ C, int M,
    int N, int K, const __hip_bfloat16* __restrict__ resid) {
  __shared__ __align__(16) short As[128 * 32];
  __shared__ __align__(16) short Bs[128 * 32];
  const int tid = threadIdx.x;
  const int w = tid >> 6, l = tid & 63;
  const int lane16 = l & 15, quad = l >> 4;
  const int wr = w >> 1, wc = w & 1;
  const int m0 = blockIdx.y * 128, n0 = blockIdx.x * 128;
  if constexpr (EPI == 3) W += (size_t)blockIdx.z * 65536;

  // staging geometry: thread owns global 16B chunks (gm,gc) and (gm+64,gc)
  const int q = w * 64 + l;
  const int gm = q >> 2, gc = q & 3;
  const int sc = gc ^ ((gm >> 1) & 3);  // swizzled chunk slot (same for gm+64)
  const unsigned short* Ag0 =
      (const unsigned short*)A + (size_t)(m0 + gm) * K + gc * 8;
  const unsigned short* Ag1 = Ag0 + (size_t)64 * K;
  const unsigned short* Bg0 =
      (const unsigned short*)W + (size_t)(n0 + gm) * K + gc * 8;
  const unsigned short* Bg1 = Bg0 + (size_t)64 * K;

  floatx4 acc[4][4];
#pragma unroll
  for (int i = 0; i < 4; i++)
#pragma unroll
    for (int j = 0; j < 4; j++) acc[i][j] = (floatx4)0.f;

  int4 ra0 = *(const int4*)(Ag0);
  int4 ra1 = *(const int4*)(Ag1);
  int4 rb0 = *(const int4*)(Bg0);
  int4 rb1 = *(const int4*)(Bg1);

  for (int k0 = 0; k0 < K; k0 += 32) {
    *(int4*)&As[gm * 32 + sc * 8] = ra0;
    *(int4*)&As[(gm + 64) * 32 + sc * 8] = ra1;
    *(int4*)&Bs[gm * 32 + sc * 8] = rb0;
    *(int4*)&Bs[(gm + 64) * 32 + sc * 8] = rb1;
    __syncthreads();
    if (k0 + 32 < K) {
      ra0 = *(const int4*)(Ag0 + k0 + 32);
      ra1 = *(const int4*)(Ag1 + k0 + 32);
      rb0 = *(const int4*)(Bg0 + k0 + 32);
      rb1 = *(const int4*)(Bg1 + k0 + 32);
    }
    short8 af[4], bfr[4];
#pragma unroll
    for (int i = 0; i < 4; i++) {
      const int ma = wr * 64 + i * 16 + lane16;
      const int ca = quad ^ ((ma >> 1) & 3);
      af[i] = *(const short8*)&As[ma * 32 + ca * 8];
      const int nb = wc * 64 + i * 16 + lane16;
      const int cb = quad ^ ((nb >> 1) & 3);
      bfr[i] = *(const short8*)&Bs[nb * 32 + cb * 8];
    }
#pragma unroll
    for (int i = 0; i < 4; i++)
#pragma unroll
      for (int j = 0; j < 4; j++)
        acc[i][j] =
            __builtin_amdgcn_mfma_f32_16x16x32_bf16(af[i], bfr[j], acc[i][j], 0, 0, 0);
    __syncthreads();
  }

  // epilogue: D row = (lane>>4)*4 + r, col = lane&15 within each 16x16 frag
#pragma unroll
  for (int j = 0; j < 4; j++) {
    const int col = n0 + wc * 64 + j * 16 + lane16;
    const float bj = bias[col];
#pragma unroll
    for (int i = 0; i < 4; i++) {
#pragma unroll
      for (int r = 0; r < 4; r++) {
        const int row = m0 + wr * 64 + i * 16 + quad * 4 + r;
        float v = acc[i][j][r] + bj;
        if constexpr (EPI == 1) v += __bfloat162float(resid[(size_t)row * N + col]);
        if constexpr (EPI == 2) v = gelu_exact(v);
        if constexpr (EPI == 3) {
          const int bI = row / Np, nr = row % Np;
          const int aa = nr / 28, cc = nr % 28;
          const int rr = blockIdx.z >> 1, ss = blockIdx.z & 1;
          C[(((size_t)(bI * Hdim + 2 * aa + rr)) * Wdim + 2 * cc + ss) * Cdim +
            col] = __float2bfloat16(v);
        } else {
          C[(size_t)row * N + col] = __float2bfloat16(v);
        }
      }
    }
  }
}

// ---------------------------------------------------------------------------
// Attention: one block per (b,h); bf16 qkv in, bf16 attout.
// ---------------------------------------------------------------------------
__global__ __launch_bounds__(256) void k_attn(
    const __hip_bfloat16* __restrict__ qkv, const float* __restrict__ mask_u,
    const float* __restrict__ temp, __hip_bfloat16* __restrict__ attout) {
  const int bh = blockIdx.x;
  const int b = bh >> 3, h = bh & 7;
  const int tid = threadIdx.x;
  __shared__ float qs[32][66], ks[32][66], vs[32][66];
  __shared__ float Smat[32][33];
  __shared__ float qn[32], kn[32];

  const size_t base = (size_t)b * Np * 768 + h * 32;
  const int d = tid >> 3, e4 = tid & 7;
  const int ld = tid & 31, lj = tid >> 5;

  float s4[4] = {0.f, 0.f, 0.f, 0.f};
  float nrm = 0.0f;

  for (int n0 = 0; n0 < Np; n0 += 64) {
#pragma unroll
    for (int it = 0; it < 8; it++) {
      const int j = lj + it * 8;
      const int n = n0 + j;
      float qv = 0.f, kv = 0.f;
      if (n < Np) {
        qv = __bfloat162float(qkv[base + (size_t)n * 768 + ld]);
        kv = __bfloat162float(qkv[base + (size_t)n * 768 + 256 + ld]);
      }
      qs[ld][j] = qv;
      ks[ld][j] = kv;
    }
    __syncthreads();
#pragma unroll 4
    for (int j = 0; j < 64; j++) {
      const float qv = qs[d][j];
#pragma unroll
      for (int u = 0; u < 4; u++) s4[u] = fmaf(qv, ks[e4 * 4 + u][j], s4[u]);
    }
    if (tid < 32) {
      for (int j = 0; j < 64; j++) { const float q = qs[tid][j]; nrm = fmaf(q, q, nrm); }
    } else if (tid < 64) {
      for (int j = 0; j < 64; j++) { const float kk = ks[tid - 32][j]; nrm = fmaf(kk, kk, nrm); }
    }
    __syncthreads();
  }

  if (tid < 32) qn[tid] = nrm;
  else if (tid < 64) kn[tid - 32] = nrm;
  __syncthreads();

  {
    const float tmp = temp[h];
    const float qd = fmaxf(sqrtf(qn[d]), 1e-12f);
#pragma unroll
    for (int u = 0; u < 4; u++) {
      const int e = e4 * 4 + u;
      const float ke = fmaxf(sqrtf(kn[e]), 1e-12f);
      float val = s4[u] / (qd * ke) * tmp;
      const float mu = mask_u[(size_t)bh * 1024 + d * 32 + e];
      if (mu < 0.2f) val -= 1e12f;
      Smat[d][e] = val;
    }
  }
  __syncthreads();

  if (tid < 32) {
    float mx = -1e30f;
#pragma unroll
    for (int e = 0; e < 32; e++) mx = fmaxf(mx, Smat[tid][e]);
    float sum = 0.f;
    float ex[32];
#pragma unroll
    for (int e = 0; e < 32; e++) {
      const float ev = expf(Smat[tid][e] - mx);
      ex[e] = ev;
      sum += ev;
    }
    const float inv = 1.0f / sum;
#pragma unroll
    for (int e = 0; e < 32; e++) Smat[tid][e] = ex[e] * inv;
  }
  __syncthreads();

  const int d2 = tid & 31, jj = tid >> 5;
  float P[32];
#pragma unroll
  for (int e = 0; e < 32; e++) P[e] = Smat[d2][e];
  const size_t vbase = base + 512;
  const size_t obase = (size_t)b * Np * Cdim + h * 32;

  for (int n0 = 0; n0 < Np; n0 += 64) {
#pragma unroll
    for (int it = 0; it < 8; it++) {
      const int j = lj + it * 8;
      const int n = n0 + j;
      vs[ld][j] = (n < Np) ? __bfloat162float(qkv[vbase + (size_t)n * 768 + ld]) : 0.f;
    }
    __syncthreads();
    float o[8] = {0.f, 0.f, 0.f, 0.f, 0.f, 0.f, 0.f, 0.f};
#pragma unroll
    for (int e = 0; e < 32; e++) {
      const float pp = P[e];
#pragma unroll
      for (int u = 0; u < 8; u++) o[u] = fmaf(pp, vs[e][jj * 8 + u], o[u]);
    }
#pragma unroll
    for (int u = 0; u < 8; u++) {
      const int n = n0 + jj * 8 + u;
      if (n < Np) attout[obase + (size_t)n * Cdim + d2] = __float2bfloat16(o[u]);
    }
    __syncthreads();
  }
}

// ---------------------------------------------------------------------------
// LN2: per NHWC row of u (bf16), write normalized bf16. One wave per row.
// (ushort4 here is intentional: 4 bf16 = 8 B per lane, 64 lanes = 256 ch.)
// ---------------------------------------------------------------------------
__global__ __launch_bounds__(256) void k_ln2(const __hip_bfloat16* __restrict__ u,
                                             const float* __restrict__ g2,
                                             const float* __restrict__ b2,
                                             __hip_bfloat16* __restrict__ o) {
  const int row = blockIdx.x * 4 + (threadIdx.x >> 6);
  const int lane = threadIdx.x & 63;
  const unsigned short* ur = (const unsigned short*)u + (size_t)row * Cdim;
  const ushort4 raw = *(const ushort4*)(ur + lane * 4);
  float v[4];
  v[0] = __bfloat162float(*(const __hip_bfloat16*)&raw.x);
  v[1] = __bfloat162float(*(const __hip_bfloat16*)&raw.y);
  v[2] = __bfloat162float(*(const __hip_bfloat16*)&raw.z);
  v[3] = __bfloat162float(*(const __hip_bfloat16*)&raw.w);
  float s1 = v[0] + v[1] + v[2] + v[3];
  float s2 = v[0] * v[0] + v[1] * v[1] + v[2] * v[2] + v[3] * v[3];
#pragma unroll
  for (int off = 32; off > 0; off >>= 1) {
    s1 += __shfl_down(s1, off);
    s2 += __shfl_down(s2, off);
  }
  s1 = __shfl(s1, 0);
  s2 = __shfl(s2, 0);
  const float m = s1 * (1.f / 256.f);
  const float var = s2 * (1.f / 256.f) - m * m;
  const float rstd = rsqrtf(var + 1e-6f);
  const float4 g = *(const float4*)&g2[lane * 4];
  const float4 bb = *(const float4*)&b2[lane * 4];
  ushort4 ov;
  __hip_bfloat16 t0 = __float2bfloat16((v[0] - m) * rstd * g.x + bb.x);
  __hip_bfloat16 t1 = __float2bfloat16((v[1] - m) * rstd * g.y + bb.y);
  __hip_bfloat16 t2 = __float2bfloat16((v[2] - m) * rstd * g.z + bb.z);
  __hip_bfloat16 t3 = __float2bfloat16((v[3] - m) * rstd * g.w + bb.w);
  ov.x = *(unsigned short*)&t0;
  ov.y = *(unsigned short*)&t1;
  ov.z = *(unsigned short*)&t2;
  ov.w = *(unsigned short*)&t3;
  *(ushort4*)((unsigned short*)o + (size_t)row * Cdim + lane * 4) = ov;
}

// ---------------------------------------------------------------------------
// Final: out[b,c,h,w] = x[b,c,h,w] + y_bf16[b,h,w,c]  (LDS transpose tile)
// ---------------------------------------------------------------------------
__global__ __launch_bounds__(256) void k_final(const float* __restrict__ x,
                                               const __hip_bfloat16* __restrict__ y,
                                               float* __restrict__ out) {
  __shared__ float tile[64][65];
  const int hw0 = blockIdx.x * 64;
  const int c0 = blockIdx.y * 64;
  const int b = blockIdx.z;
  const int tid = threadIdx.x;
  {
    const int ci = tid & 63;
    const int hwB = tid >> 6;
#pragma unroll
    for (int it = 0; it < 16; it++) {
      const int hwi = hwB + it * 4;
      tile[hwi][ci] =
          __bfloat162float(y[((size_t)b * 3136 + hw0 + hwi) * Cdim + c0 + ci]);
    }
  }
  __syncthreads();
  {
    const int hwi = tid & 63;
    const int cB = tid >> 6;
#pragma unroll
    for (int it = 0; it < 16; it++) {
      const int ci = cB + it * 4;
      const size_t o = ((size_t)(b * Cdim + c0 + ci)) * 3136 + hw0 + hwi;
      out[o] = x[o] + tile[hwi][ci];
    }
  }
}

// ---------------------------------------------------------------------------
// Host launcher
// ---------------------------------------------------------------------------
extern "C" void kernel_launch(void* const* d_in, const int* in_sizes, int n_in,
                              void* d_out, int out_size, void* d_ws,
                              size_t ws_size, hipStream_t stream) {
  const float* x      = (const float*)d_in[0];
  const float* mask_u = (const float*)d_in[1];
  const float* dw_w   = (const float*)d_in[2];
  const float* dw_b   = (const float*)d_in[3];
  const float* g1     = (const float*)d_in[4];
  const float* b1     = (const float*)d_in[5];
  const float* qkv_w  = (const float*)d_in[6];
  const float* qkv_b  = (const float*)d_in[7];
  const float* temp   = (const float*)d_in[8];
  const float* proj_w = (const float*)d_in[9];
  const float* proj_b = (const float*)d_in[10];
  const float* ct_w   = (const float*)d_in[11];
  const float* ct_b   = (const float*)d_in[12];
  const float* g2     = (const float*)d_in[13];
  const float* b2     = (const float*)d_in[14];
  const float* pw1_w  = (const float*)d_in[15];
  const float* pw1_b  = (const float*)d_in[16];
  const float* pw2_w  = (const float*)d_in[17];
  const float* pw2_b  = (const float*)d_in[18];

  char* wsb = (char*)d_ws;
  // byte-offset layout with lifetime aliasing (peak ~105 MB):
  __hip_bfloat16* u      = (__hip_bfloat16*)(wsb + 0);          // 25,690,112
  __hip_bfloat16* rbuf   = (__hip_bfloat16*)(wsb + 25690112);   //  6,422,528
  float*          p      = (float*)        (wsb + 32112640);    // 12,845,056
  __hip_bfloat16* t      = (__hip_bfloat16*)(wsb + 44957696);   //  6,422,528
  __hip_bfloat16* ln2    = (__hip_bfloat16*)(wsb + 25690112);   // 25,690,112 (after r/p/t die)
  __hip_bfloat16* qkvb   = (__hip_bfloat16*)(wsb + 51380224);   // 19,267,584
  __hip_bfloat16* h1     = (__hip_bfloat16*)(wsb + 51380224);   // 25,690,112 (after qkv dies)
  __hip_bfloat16* attout = (__hip_bfloat16*)(wsb + 77070336);   //  6,422,528
  __hip_bfloat16* y      = (__hip_bfloat16*)(wsb + 77070336);   // 25,690,112 (after attout dies)
  __hip_bfloat16* wb     = (__hip_bfloat16*)(wsb + 102760448);  //  2,097,152
  float* out = (float*)d_out;

  const __hip_bfloat16* wqkv = wb;
  const __hip_bfloat16* wproj = wb + 196608;
  const __hip_bfloat16* wpw1 = wb + 262144;
  const __hip_bfloat16* wpw2 = wb + 524288;
  const __hip_bfloat16* wct = wb + 786432;

  // 0) weights -> bf16
  k_prep<<<dim3(4096), 256, 0, stream>>>(qkv_w, proj_w, pw1_w, pw2_w, ct_w, wb);
  // 1) dw conv + residual + pool -> p
  k_pool<<<dim3(4096), 256, 0, stream>>>(x, dw_w, dw_b, p);
  // 2) transpose + LN1 -> t
  k_lnt<<<dim3(13, Bdim), 256, 0, stream>>>(p, g1, b1, t);
  // 3) qkv GEMM
  mm_bf16<0><<<dim3(6, 98), 256, 0, stream>>>(t, wqkv, qkv_b, qkvb, M_TOK, 768,
                                              256, nullptr);
  // 4) attention
  k_attn<<<dim3(128), 256, 0, stream>>>(qkvb, mask_u, temp, attout);
  // 5) proj GEMM + t residual -> r
  mm_bf16<1><<<dim3(2, 98), 256, 0, stream>>>(attout, wproj, proj_b, rbuf,
                                              M_TOK, 256, 256, t);
  // 6) conv-transpose (4 quadrant GEMMs) -> u (NHWC bf16)
  mm_bf16<3><<<dim3(2, 98, 4), 256, 0, stream>>>(rbuf, wct, ct_b, u, M_TOK, 256,
                                                 256, nullptr);
  // 7) LN2 -> ln2
  k_ln2<<<dim3(M_PIX / 4), 256, 0, stream>>>(u, g2, b2, ln2);
  // 8) MLP in 4 chunks
  for (int ch = 0; ch < 4; ch++) {
    const __hip_bfloat16* lc = ln2 + (size_t)ch * M_TOK * Cdim;
    __hip_bfloat16* yc = y + (size_t)ch * M_TOK * Cdim;
    mm_bf16<2><<<dim3(8, 98), 256, 0, stream>>>(lc, wpw1, pw1_b, h1, M_TOK,
                                                1024, 256, nullptr);
    mm_bf16<0><<<dim3(2, 98), 256, 0, stream>>>(h1, wpw2, pw2_b, yc, M_TOK, 256,
                                                1024, nullptr);
  }
  // 9) out = x + transpose(y)
  k_final<<<dim3(49, 4, Bdim), 256, 0, stream>>>(x, y, out);
}

// Round 4
// 530.665 us; speedup vs baseline: 2.8011x; 1.0817x over previous
//
#include <hip/hip_runtime.h>
#include <hip/hip_bf16.h>
#include <math.h>

// ---------------------------------------------------------------------------
// GFA encoder forward. bf16-MFMA GEMM pipeline + parallelized attention.
// B=16, C=256, H=W=56, Hp=Wp=28, N=784, heads=8, dh=32, E=4.
// ---------------------------------------------------------------------------

#define Bdim 16
#define Cdim 256
#define Hdim 56
#define Wdim 56
#define Np 784
#define M_TOK 12544
#define M_PIX 50176

typedef __attribute__((ext_vector_type(8))) short short8;
typedef __attribute__((ext_vector_type(4))) float floatx4;

__device__ __forceinline__ float gelu_exact(float x) {
  return 0.5f * x * (1.0f + erff(x * 0.70710678118654752f));
}

// async global->LDS, 16 bytes per lane. LDS dest must be uniform base +
// lane*16 within each wave (it is: dest = base + tid*16).
__device__ __forceinline__ void gl_lds16(const void* g, void* l) {
  __builtin_amdgcn_global_load_lds(
      (const __attribute__((address_space(1))) unsigned int*)g,
      (__attribute__((address_space(3))) unsigned int*)l, 16, 0, 0);
}

// ---------------------------------------------------------------------------
// Weight prep: cast all GEMM weights to bf16 (ct_w restructured to [rs][n][k]).
// ---------------------------------------------------------------------------
__global__ __launch_bounds__(256) void k_prep(
    const float* __restrict__ qkv_w, const float* __restrict__ proj_w,
    const float* __restrict__ pw1_w, const float* __restrict__ pw2_w,
    const float* __restrict__ ct_w, __hip_bfloat16* __restrict__ wb) {
  int i = blockIdx.x * 256 + threadIdx.x;
  if (i < 196608) { wb[i] = __float2bfloat16(qkv_w[i]); return; }
  i -= 196608;
  if (i < 65536) { (wb + 196608)[i] = __float2bfloat16(proj_w[i]); return; }
  i -= 65536;
  if (i < 262144) { (wb + 262144)[i] = __float2bfloat16(pw1_w[i]); return; }
  i -= 262144;
  if (i < 262144) { (wb + 524288)[i] = __float2bfloat16(pw2_w[i]); return; }
  i -= 262144;
  const int rs = i >> 16, rem = i & 65535, n = rem >> 8, k = rem & 255;
  (wb + 786432)[i] = __float2bfloat16(ct_w[k * 1024 + n * 4 + rs]);
}

// ---------------------------------------------------------------------------
// K1a: depthwise 3x3 + bias + residual + 2x2 avg pool. One block per (b,c).
// ---------------------------------------------------------------------------
__global__ __launch_bounds__(256) void k_pool(const float* __restrict__ x,
                                              const float* __restrict__ dww,
                                              const float* __restrict__ dwb,
                                              float* __restrict__ p) {
  __shared__ float xs[58 * 60];
  const int bid = blockIdx.x;  // b*256 + c
  const int c = bid & 255;
  const int tid = threadIdx.x;
  const float* xp = x + (size_t)bid * 3136;
  for (int i = tid; i < 58 * 60; i += 256) xs[i] = 0.f;
  __syncthreads();
  for (int i = tid; i < 3136; i += 256) {
    const int r = i / 56, cc = i % 56;
    xs[(r + 1) * 60 + (cc + 1)] = xp[i];
  }
  __syncthreads();
  float w[9];
#pragma unroll
  for (int i = 0; i < 9; i++) w[i] = dww[c * 9 + i];
  const float bias = dwb[c];
  float* pp = p + (size_t)bid * Np;
  for (int n = tid; n < Np; n += 256) {
    const int a = n / 28, bb = n % 28;
    const int r0 = 2 * a, c0 = 2 * bb;
    float acc = 0.f;
#pragma unroll
    for (int pi = 0; pi < 2; pi++)
#pragma unroll
      for (int pj = 0; pj < 2; pj++) {
        float conv = bias;
#pragma unroll
        for (int rr = 0; rr < 3; rr++)
#pragma unroll
          for (int ss = 0; ss < 3; ss++)
            conv = fmaf(xs[(r0 + pi + rr) * 60 + c0 + pj + ss], w[rr * 3 + ss],
                        conv);
        acc += conv + xs[(r0 + pi + 1) * 60 + (c0 + pj + 1)];
      }
    pp[n] = acc * 0.25f;
  }
}

// ---------------------------------------------------------------------------
// K1b: transpose p [B,C,N] -> t [B,N,C] with LayerNorm over C. bf16 out.
// ---------------------------------------------------------------------------
__global__ __launch_bounds__(256) void k_lnt(const float* __restrict__ p,
                                             const float* __restrict__ g1,
                                             const float* __restrict__ b1,
                                             __hip_bfloat16* __restrict__ t) {
  __shared__ float xs[256][65];
  __shared__ float red[4][64][2];
  __shared__ float ms[64][2];
  const int n0 = blockIdx.x * 64;
  const int b = blockIdx.y;
  const int tid = threadIdx.x;
  const int lane = tid & 63, grp = tid >> 6;
  const int n = n0 + lane;
  const bool nok = (n < Np);
  float s1 = 0.f, s2 = 0.f;
  for (int it = 0; it < 64; it++) {
    const int c = grp * 64 + it;
    const float v = nok ? p[((size_t)b * Cdim + c) * Np + n] : 0.f;
    xs[c][lane] = v;
    s1 += v;
    s2 += v * v;
  }
  red[grp][lane][0] = s1;
  red[grp][lane][1] = s2;
  __syncthreads();
  if (tid < 64) {
    const float a1 =
        red[0][tid][0] + red[1][tid][0] + red[2][tid][0] + red[3][tid][0];
    const float a2 =
        red[0][tid][1] + red[1][tid][1] + red[2][tid][1] + red[3][tid][1];
    const float m = a1 * (1.f / 256.f);
    const float var = a2 * (1.f / 256.f) - m * m;
    ms[tid][0] = m;
    ms[tid][1] = rsqrtf(var + 1e-6f);
  }
  __syncthreads();
  const float gg = g1[tid], bb = b1[tid];
  const int nlim = (Np - n0 < 64) ? (Np - n0) : 64;
  for (int tok = 0; tok < nlim; tok++) {
    const float v = (xs[tid][tok] - ms[tok][0]) * ms[tok][1] * gg + bb;
    t[((size_t)b * Np + n0 + tok) * Cdim + tid] = __float2bfloat16(v);
  }
}

// ---------------------------------------------------------------------------
// bf16 MFMA GEMM: C = A[M,K] @ W[N,K]^T + bias. 128x128 tile, BK=32,
// 4 waves 2x2, 16x16x32 MFMA, global_load_lds(16B) staging (m97 structure).
// EPI: 0 bf16 store; 1 +resid bf16; 2 GELU bf16; 3 ct-quadrant scatter bf16.
// ---------------------------------------------------------------------------
template <int EPI>
__global__ __launch_bounds__(256) void mm_bf16(
    const __hip_bfloat16* __restrict__ A, const __hip_bfloat16* __restrict__ W,
    const float* __restrict__ bias, __hip_bfloat16* __restrict__ C, int M,
    int N, int K, const __hip_bfloat16* __restrict__ resid) {
  __shared__ __align__(16) short As[128 * 32];
  __shared__ __align__(16) short Bs[128 * 32];
  const int tid = threadIdx.x;
  const int w = tid >> 6, l = tid & 63;
  const int lane16 = l & 15, quad = l >> 4;
  const int wr = w >> 1, wc = w & 1;
  const int m0 = blockIdx.y * 128, n0 = blockIdx.x * 128;
  if constexpr (EPI == 3) W += (size_t)blockIdx.z * 65536;

  // thread tid stages 16B chunks tid and tid+256 (rows gm, gm+64)
  const int gm = tid >> 2, gc = tid & 3;
  const __hip_bfloat16* Ag0 = A + (size_t)(m0 + gm) * K + gc * 8;
  const __hip_bfloat16* Ag1 = Ag0 + (size_t)64 * K;
  const __hip_bfloat16* Bg0 = W + (size_t)(n0 + gm) * K + gc * 8;
  const __hip_bfloat16* Bg1 = Bg0 + (size_t)64 * K;
  short* Asl0 = &As[tid * 8];
  short* Asl1 = &As[(tid + 256) * 8];
  short* Bsl0 = &Bs[tid * 8];
  short* Bsl1 = &Bs[(tid + 256) * 8];

  floatx4 acc[4][4];
#pragma unroll
  for (int i = 0; i < 4; i++)
#pragma unroll
    for (int j = 0; j < 4; j++) acc[i][j] = (floatx4)0.f;

  for (int k0 = 0; k0 < K; k0 += 32) {
    gl_lds16(Ag0 + k0, Asl0);
    gl_lds16(Ag1 + k0, Asl1);
    gl_lds16(Bg0 + k0, Bsl0);
    gl_lds16(Bg1 + k0, Bsl1);
    __syncthreads();
    short8 af[4], bfr[4];
#pragma unroll
    for (int i = 0; i < 4; i++) {
      const int ma = wr * 64 + i * 16 + lane16;
      af[i] = *(const short8*)&As[ma * 32 + quad * 8];
      const int nb = wc * 64 + i * 16 + lane16;
      bfr[i] = *(const short8*)&Bs[nb * 32 + quad * 8];
    }
#pragma unroll
    for (int i = 0; i < 4; i++)
#pragma unroll
      for (int j = 0; j < 4; j++)
        acc[i][j] = __builtin_amdgcn_mfma_f32_16x16x32_bf16(af[i], bfr[j],
                                                            acc[i][j], 0, 0, 0);
    __syncthreads();
  }

  // epilogue: D row = (lane>>4)*4 + r, col = lane&15 within each 16x16 frag
#pragma unroll
  for (int j = 0; j < 4; j++) {
    const int col = n0 + wc * 64 + j * 16 + lane16;
    const float bj = bias[col];
#pragma unroll
    for (int i = 0; i < 4; i++) {
#pragma unroll
      for (int r = 0; r < 4; r++) {
        const int row = m0 + wr * 64 + i * 16 + quad * 4 + r;
        float v = acc[i][j][r] + bj;
        if constexpr (EPI == 1) v += __bfloat162float(resid[(size_t)row * N + col]);
        if constexpr (EPI == 2) v = gelu_exact(v);
        if constexpr (EPI == 3) {
          const int bI = row / Np, nr = row % Np;
          const int aa = nr / 28, cc = nr % 28;
          const int rr = blockIdx.z >> 1, ss = blockIdx.z & 1;
          C[(((size_t)(bI * Hdim + 2 * aa + rr)) * Wdim + 2 * cc + ss) * Cdim +
            col] = __float2bfloat16(v);
        } else {
          C[(size_t)row * N + col] = __float2bfloat16(v);
        }
      }
    }
  }
}

// ---------------------------------------------------------------------------
// Attention stage 1: partial Gram (32x32) + partial q/k norms per
// (bh, 112-token chunk). part row: [0..1023]=S, [1024..1055]=qn, [1056..]=kn.
// ---------------------------------------------------------------------------
__global__ __launch_bounds__(256) void k_gram(
    const __hip_bfloat16* __restrict__ qkv, float* __restrict__ part) {
  __shared__ float qs[32][113], ks[32][113];
  const int c = blockIdx.x;   // 0..6
  const int bh = blockIdx.y;  // 0..127
  const int b = bh >> 3, h = bh & 7;
  const int tid = threadIdx.x;
  const size_t base = (size_t)b * Np * 768 + h * 32;
  const int n0 = c * 112;
  const int ld = tid & 31, lj = tid >> 5;
#pragma unroll
  for (int it = 0; it < 14; it++) {
    const int jt = lj + it * 8;
    const size_t off = base + (size_t)(n0 + jt) * 768 + ld;
    qs[ld][jt] = __bfloat162float(qkv[off]);
    ks[ld][jt] = __bfloat162float(qkv[off + 256]);
  }
  __syncthreads();
  const int d = tid >> 3, e4 = tid & 7;
  float s4[4] = {0.f, 0.f, 0.f, 0.f};
#pragma unroll 4
  for (int j = 0; j < 112; j++) {
    const float qv = qs[d][j];
#pragma unroll
    for (int u = 0; u < 4; u++) s4[u] = fmaf(qv, ks[e4 * 4 + u][j], s4[u]);
  }
  float* pp = part + ((size_t)bh * 7 + c) * 1088;
  *(float4*)&pp[d * 32 + e4 * 4] = *(float4*)s4;
  if (tid < 64) {
    float nrm = 0.f;
    if (tid < 32) {
      for (int j = 0; j < 112; j++) { const float q = qs[tid][j]; nrm = fmaf(q, q, nrm); }
      pp[1024 + tid] = nrm;
    } else {
      for (int j = 0; j < 112; j++) { const float k = ks[tid - 32][j]; nrm = fmaf(k, k, nrm); }
      pp[1056 + (tid - 32)] = nrm;
    }
  }
}

// ---------------------------------------------------------------------------
// Attention stage 2: reduce partials, normalize, temp, mask, softmax -> P.
// One block per bh; thread = (row d = tid>>3, 4 cols e4*4..e4*4+3).
// ---------------------------------------------------------------------------
__global__ __launch_bounds__(256) void k_soft(const float* __restrict__ part,
                                              const float* __restrict__ mask_u,
                                              const float* __restrict__ temp,
                                              float* __restrict__ P) {
  const int bh = blockIdx.x;
  const int h = bh & 7;
  const int tid = threadIdx.x;
  const int d = tid >> 3, e4 = tid & 7;
  float4 S = {0.f, 0.f, 0.f, 0.f};
  float qn = 0.f;
  float4 kn = {0.f, 0.f, 0.f, 0.f};
  for (int c = 0; c < 7; c++) {
    const float* pp = part + ((size_t)bh * 7 + c) * 1088;
    const float4 s = *(const float4*)&pp[d * 32 + e4 * 4];
    S.x += s.x; S.y += s.y; S.z += s.z; S.w += s.w;
    qn += pp[1024 + d];
    const float4 k4 = *(const float4*)&pp[1056 + e4 * 4];
    kn.x += k4.x; kn.y += k4.y; kn.z += k4.z; kn.w += k4.w;
  }
  const float tmp = temp[h];
  const float qd = fmaxf(sqrtf(qn), 1e-12f);
  float val[4];
  val[0] = S.x / (qd * fmaxf(sqrtf(kn.x), 1e-12f)) * tmp;
  val[1] = S.y / (qd * fmaxf(sqrtf(kn.y), 1e-12f)) * tmp;
  val[2] = S.z / (qd * fmaxf(sqrtf(kn.z), 1e-12f)) * tmp;
  val[3] = S.w / (qd * fmaxf(sqrtf(kn.w), 1e-12f)) * tmp;
  const float4 mu = *(const float4*)&mask_u[(size_t)bh * 1024 + d * 32 + e4 * 4];
  if (mu.x < 0.2f) val[0] -= 1e12f;
  if (mu.y < 0.2f) val[1] -= 1e12f;
  if (mu.z < 0.2f) val[2] -= 1e12f;
  if (mu.w < 0.2f) val[3] -= 1e12f;
  // row softmax across the 8-lane group (each lane holds 4 cols)
  float mx = fmaxf(fmaxf(val[0], val[1]), fmaxf(val[2], val[3]));
  mx = fmaxf(mx, __shfl_xor(mx, 1));
  mx = fmaxf(mx, __shfl_xor(mx, 2));
  mx = fmaxf(mx, __shfl_xor(mx, 4));
  float ex[4];
  float sum = 0.f;
#pragma unroll
  for (int u = 0; u < 4; u++) { ex[u] = expf(val[u] - mx); sum += ex[u]; }
  sum += __shfl_xor(sum, 1);
  sum += __shfl_xor(sum, 2);
  sum += __shfl_xor(sum, 4);
  const float inv = 1.0f / sum;
  float4 out;
  out.x = ex[0] * inv; out.y = ex[1] * inv; out.z = ex[2] * inv; out.w = ex[3] * inv;
  *(float4*)&P[(size_t)bh * 1024 + d * 32 + e4 * 4] = out;
}

// ---------------------------------------------------------------------------
// Attention stage 3: out = P @ v per (bh, 98-token chunk) -> attout[B,N,C].
// ---------------------------------------------------------------------------
__global__ __launch_bounds__(256) void k_pv(const float* __restrict__ P,
                                            const __hip_bfloat16* __restrict__ qkv,
                                            __hip_bfloat16* __restrict__ attout) {
  __shared__ float vs[32][99];
  const int ch = blockIdx.x;  // 0..7
  const int bh = blockIdx.y;
  const int b = bh >> 3, h = bh & 7;
  const int tid = threadIdx.x;
  const int d = tid & 31, jrow = tid >> 5;
  const int n0 = ch * 98;
  const size_t vbase = (size_t)b * Np * 768 + h * 32 + 512;
  const size_t obase = (size_t)b * Np * Cdim + h * 32;

  float Pr[32];
  const float* Pw = P + (size_t)bh * 1024 + d * 32;
#pragma unroll
  for (int e4 = 0; e4 < 8; e4++) {
    const float4 p4 = *(const float4*)&Pw[e4 * 4];
    Pr[e4 * 4 + 0] = p4.x; Pr[e4 * 4 + 1] = p4.y;
    Pr[e4 * 4 + 2] = p4.z; Pr[e4 * 4 + 3] = p4.w;
  }
#pragma unroll
  for (int it = 0; it < 13; it++) {
    const int jt = jrow + it * 8;
    if (jt < 98) vs[d][jt] = __bfloat162float(qkv[vbase + (size_t)(n0 + jt) * 768 + d]);
  }
  __syncthreads();
#pragma unroll
  for (int it = 0; it < 13; it++) {
    const int jt = jrow + it * 8;
    if (jt < 98) {
      float o = 0.f;
#pragma unroll
      for (int e = 0; e < 32; e++) o = fmaf(Pr[e], vs[e][jt], o);
      attout[obase + (size_t)(n0 + jt) * Cdim + d] = __float2bfloat16(o);
    }
  }
}

// ---------------------------------------------------------------------------
// LN2: per NHWC row of u (bf16), write normalized bf16. One wave per row.
// ---------------------------------------------------------------------------
__global__ __launch_bounds__(256) void k_ln2(const __hip_bfloat16* __restrict__ u,
                                             const float* __restrict__ g2,
                                             const float* __restrict__ b2,
                                             __hip_bfloat16* __restrict__ o) {
  const int row = blockIdx.x * 4 + (threadIdx.x >> 6);
  const int lane = threadIdx.x & 63;
  const unsigned short* ur = (const unsigned short*)u + (size_t)row * Cdim;
  const ushort4 raw = *(const ushort4*)(ur + lane * 4);
  float v[4];
  v[0] = __bfloat162float(*(const __hip_bfloat16*)&raw.x);
  v[1] = __bfloat162float(*(const __hip_bfloat16*)&raw.y);
  v[2] = __bfloat162float(*(const __hip_bfloat16*)&raw.z);
  v[3] = __bfloat162float(*(const __hip_bfloat16*)&raw.w);
  float s1 = v[0] + v[1] + v[2] + v[3];
  float s2 = v[0] * v[0] + v[1] * v[1] + v[2] * v[2] + v[3] * v[3];
#pragma unroll
  for (int off = 32; off > 0; off >>= 1) {
    s1 += __shfl_down(s1, off);
    s2 += __shfl_down(s2, off);
  }
  s1 = __shfl(s1, 0);
  s2 = __shfl(s2, 0);
  const float m = s1 * (1.f / 256.f);
  const float var = s2 * (1.f / 256.f) - m * m;
  const float rstd = rsqrtf(var + 1e-6f);
  const float4 g = *(const float4*)&g2[lane * 4];
  const float4 bb = *(const float4*)&b2[lane * 4];
  ushort4 ov;
  __hip_bfloat16 t0 = __float2bfloat16((v[0] - m) * rstd * g.x + bb.x);
  __hip_bfloat16 t1 = __float2bfloat16((v[1] - m) * rstd * g.y + bb.y);
  __hip_bfloat16 t2 = __float2bfloat16((v[2] - m) * rstd * g.z + bb.z);
  __hip_bfloat16 t3 = __float2bfloat16((v[3] - m) * rstd * g.w + bb.w);
  ov.x = *(unsigned short*)&t0;
  ov.y = *(unsigned short*)&t1;
  ov.z = *(unsigned short*)&t2;
  ov.w = *(unsigned short*)&t3;
  *(ushort4*)((unsigned short*)o + (size_t)row * Cdim + lane * 4) = ov;
}

// ---------------------------------------------------------------------------
// Final: out[b,c,h,w] = x[b,c,h,w] + y_bf16[b,h,w,c]  (LDS transpose tile)
// ---------------------------------------------------------------------------
__global__ __launch_bounds__(256) void k_final(const float* __restrict__ x,
                                               const __hip_bfloat16* __restrict__ y,
                                               float* __restrict__ out) {
  __shared__ float tile[64][65];
  const int hw0 = blockIdx.x * 64;
  const int c0 = blockIdx.y * 64;
  const int b = blockIdx.z;
  const int tid = threadIdx.x;
  {
    const int ci = tid & 63;
    const int hwB = tid >> 6;
#pragma unroll
    for (int it = 0; it < 16; it++) {
      const int hwi = hwB + it * 4;
      tile[hwi][ci] =
          __bfloat162float(y[((size_t)b * 3136 + hw0 + hwi) * Cdim + c0 + ci]);
    }
  }
  __syncthreads();
  {
    const int hwi = tid & 63;
    const int cB = tid >> 6;
#pragma unroll
    for (int it = 0; it < 16; it++) {
      const int ci = cB + it * 4;
      const size_t o = ((size_t)(b * Cdim + c0 + ci)) * 3136 + hw0 + hwi;
      out[o] = x[o] + tile[hwi][ci];
    }
  }
}

// ---------------------------------------------------------------------------
// Host launcher
// ---------------------------------------------------------------------------
extern "C" void kernel_launch(void* const* d_in, const int* in_sizes, int n_in,
                              void* d_out, int out_size, void* d_ws,
                              size_t ws_size, hipStream_t stream) {
  const float* x      = (const float*)d_in[0];
  const float* mask_u = (const float*)d_in[1];
  const float* dw_w   = (const float*)d_in[2];
  const float* dw_b   = (const float*)d_in[3];
  const float* g1     = (const float*)d_in[4];
  const float* b1     = (const float*)d_in[5];
  const float* qkv_w  = (const float*)d_in[6];
  const float* qkv_b  = (const float*)d_in[7];
  const float* temp   = (const float*)d_in[8];
  const float* proj_w = (const float*)d_in[9];
  const float* proj_b = (const float*)d_in[10];
  const float* ct_w   = (const float*)d_in[11];
  const float* ct_b   = (const float*)d_in[12];
  const float* g2     = (const float*)d_in[13];
  const float* b2     = (const float*)d_in[14];
  const float* pw1_w  = (const float*)d_in[15];
  const float* pw1_b  = (const float*)d_in[16];
  const float* pw2_w  = (const float*)d_in[17];
  const float* pw2_b  = (const float*)d_in[18];

  char* wsb = (char*)d_ws;
  // byte-offset layout with lifetime aliasing (peak ~105 MB):
  __hip_bfloat16* u      = (__hip_bfloat16*)(wsb + 0);          // 25,690,112
  __hip_bfloat16* rbuf   = (__hip_bfloat16*)(wsb + 25690112);   //  6,422,528
  float*          p      = (float*)        (wsb + 32112640);    // 12,845,056
  __hip_bfloat16* t      = (__hip_bfloat16*)(wsb + 44957696);   //  6,422,528
  __hip_bfloat16* ln2    = (__hip_bfloat16*)(wsb + 25690112);   // (after r/p/t die)
  __hip_bfloat16* qkvb   = (__hip_bfloat16*)(wsb + 51380224);   // 19,267,584
  __hip_bfloat16* h1     = (__hip_bfloat16*)(wsb + 51380224);   // (after qkv dies)
  __hip_bfloat16* attout = (__hip_bfloat16*)(wsb + 77070336);   //  6,422,528
  __hip_bfloat16* y      = (__hip_bfloat16*)(wsb + 77070336);   // (after attout dies)
  __hip_bfloat16* wb     = (__hip_bfloat16*)(wsb + 102760448);  //  2,097,152
  // attention scratch aliases the dead p region (p dies after k_lnt):
  float* part = (float*)(wsb + 32112640);        // 896*1088 floats = 3.9 MB
  float* Pws  = part + 974848;                   // 128*1024 floats = 0.5 MB
  float* out = (float*)d_out;

  const __hip_bfloat16* wqkv = wb;
  const __hip_bfloat16* wproj = wb + 196608;
  const __hip_bfloat16* wpw1 = wb + 262144;
  const __hip_bfloat16* wpw2 = wb + 524288;
  const __hip_bfloat16* wct = wb + 786432;

  // 0) weights -> bf16
  k_prep<<<dim3(4096), 256, 0, stream>>>(qkv_w, proj_w, pw1_w, pw2_w, ct_w, wb);
  // 1) dw conv + residual + pool -> p
  k_pool<<<dim3(4096), 256, 0, stream>>>(x, dw_w, dw_b, p);
  // 2) transpose + LN1 -> t
  k_lnt<<<dim3(13, Bdim), 256, 0, stream>>>(p, g1, b1, t);
  // 3) qkv GEMM
  mm_bf16<0><<<dim3(6, 98), 256, 0, stream>>>(t, wqkv, qkv_b, qkvb, M_TOK, 768,
                                              256, nullptr);
  // 4) attention: gram partials -> softmax P -> P@V
  k_gram<<<dim3(7, 128), 256, 0, stream>>>(qkvb, part);
  k_soft<<<dim3(128), 256, 0, stream>>>(part, mask_u, temp, Pws);
  k_pv<<<dim3(8, 128), 256, 0, stream>>>(Pws, qkvb, attout);
  // 5) proj GEMM + t residual -> r
  mm_bf16<1><<<dim3(2, 98), 256, 0, stream>>>(attout, wproj, proj_b, rbuf,
                                              M_TOK, 256, 256, t);
  // 6) conv-transpose (4 quadrant GEMMs) -> u (NHWC bf16)
  mm_bf16<3><<<dim3(2, 98, 4), 256, 0, stream>>>(rbuf, wct, ct_b, u, M_TOK, 256,
                                                 256, nullptr);
  // 7) LN2 -> ln2
  k_ln2<<<dim3(M_PIX / 4), 256, 0, stream>>>(u, g2, b2, ln2);
  // 8) MLP in 4 chunks
  for (int ch = 0; ch < 4; ch++) {
    const __hip_bfloat16* lc = ln2 + (size_t)ch * M_TOK * Cdim;
    __hip_bfloat16* yc = y + (size_t)ch * M_TOK * Cdim;
    mm_bf16<2><<<dim3(8, 98), 256, 0, stream>>>(lc, wpw1, pw1_b, h1, M_TOK,
                                                1024, 256, nullptr);
    mm_bf16<0><<<dim3(2, 98), 256, 0, stream>>>(h1, wpw2, pw2_b, yc, M_TOK, 256,
                                                1024, nullptr);
  }
  // 9) out = x + transpose(y)
  k_final<<<dim3(49, 4, Bdim), 256, 0, stream>>>(x, y, out);
}